// Round 2
// baseline (17666.904 us; speedup 1.0000x reference)
//
#include <hip/hip_runtime.h>
#include <math.h>

// Problem constants
//   B=4, NB=2048, NA=NC=1024, D=1024, E=8, H=16, HD=64, TOP_K=2
// All-fp32 implementation (no MFMA): top-2 routing makes numerics precision-critical.

// ----------------------------------------------------------------------------
__global__ void zero_k(double* p) {
    if (threadIdx.x < 8) p[threadIdx.x] = 0.0;
}

// ----------------------------------------------------------------------------
// sinusoidal time embedding: emb[b][0:512]=sin(t*freq), [512:1024]=cos(t*freq)
__global__ void emb_k(const int* __restrict__ t, float* __restrict__ emb) {
    int b = blockIdx.x;
    int j = threadIdx.x; // 0..511
    float x1 = (float)(-9.210340371976184) * (float)j;  // -log(10000) * j  (fp32, like np)
    float x2 = x1 / 511.0f;
    float freq = (float)exp((double)x2);
    float tf = (float)t[b];
    float arg = tf * freq;                               // fp32 product, like np
    emb[b * 1024 + j]       = (float)sin((double)arg);
    emb[b * 1024 + 512 + j] = (float)cos((double)arg);
}

// ----------------------------------------------------------------------------
// tiny FC for the time-embedding MLP
__global__ void te_fc_k(const float* __restrict__ in, const float* __restrict__ W,
                        const float* __restrict__ bias, float* __restrict__ out,
                        int K, int N, int do_silu) {
    int b = blockIdx.x;
    int wv = threadIdx.x >> 6, lane = threadIdx.x & 63;
    const float* inb = in + (size_t)b * K;
    int n0 = blockIdx.y * 16 + wv * 4;
    for (int q = 0; q < 4; q++) {
        int n = n0 + q;
        const float* wr = W + (size_t)n * K;
        float acc = 0.f;
        for (int c = lane * 4; c < K; c += 256) {
            float4 a  = *(const float4*)(inb + c);
            float4 w4 = *(const float4*)(wr + c);
            acc += a.x * w4.x + a.y * w4.y + a.z * w4.z + a.w * w4.w;
        }
#pragma unroll
        for (int off = 1; off < 64; off <<= 1) acc += __shfl_xor(acc, off, 64);
        if (lane == 0) {
            float x = acc + bias[n];
            out[(size_t)b * N + n] = do_silu ? (x / (1.0f + expf(-x))) : x;
        }
    }
}

// ----------------------------------------------------------------------------
// fp32 GEMM: C[orow(r), col] = dot(A[r,:K], W[col,:K]) + bias[col]  (W row-major (N,K))
// 128x128 tile, BK=16, 256 threads, split 4+4 fragments, double-buffered LDS.
// GATE mode: K=3072 split across 3 A sources (tokens | ctxB | t_emb-per-batch).
// orow = base + (r>>rs)*stride + (r & ((1<<rs)-1))  (identity: rs=13, stride=0)
// colSegStride: output column c goes to C + (c>>10)*colSegStride + (c&1023)  (KV merge)
template<bool GATE, bool RELU>
__global__ __launch_bounds__(256, 3)
void gemm_k(const float* __restrict__ A0, const float* __restrict__ A1,
            const float* __restrict__ A2,
            const float* __restrict__ W, const float* __restrict__ bias,
            float* __restrict__ C, int K,
            int out_rshift, int out_stride, int out_base, size_t colSegStride)
{
    __shared__ float As[2][16][132];
    __shared__ float Bs[2][16][132];
    const int tid = threadIdx.x;
    const int tx = tid & 15, ty = tid >> 4;
    const int row0 = blockIdx.x * 128;
    const int col0 = blockIdx.y * 128;
    float acc[2][2][4][4] = {};
    float4 rA[2], rB[2];

    auto loadChunk = [&](int kk) {
#pragma unroll
        for (int tp = 0; tp < 2; tp++) {
            int idx = tid + tp * 256;    // 0..511
            int m  = idx >> 2;           // 0..127
            int k4 = (idx & 3) * 4;
            const float* Asel = A0;
            int colbase = kk;
            int arow = row0 + m;
            if (GATE) {
                int seg = kk >> 10;
                Asel = (seg == 0) ? A0 : ((seg == 1) ? A1 : A2);
                colbase = kk & 1023;
                if (seg == 2) arow = (row0 + m) >> 11;  // t_emb: one row per batch
            }
            rA[tp] = *(const float4*)(Asel + (size_t)arow * 1024 + colbase + k4);
            rB[tp] = *(const float4*)(W + (size_t)(col0 + m) * K + kk + k4);
        }
    };
    auto storeChunk = [&](int buf) {
#pragma unroll
        for (int tp = 0; tp < 2; tp++) {
            int idx = tid + tp * 256;
            int m  = idx >> 2;
            int k4 = (idx & 3) * 4;
            As[buf][k4 + 0][m] = rA[tp].x; As[buf][k4 + 1][m] = rA[tp].y;
            As[buf][k4 + 2][m] = rA[tp].z; As[buf][k4 + 3][m] = rA[tp].w;
            Bs[buf][k4 + 0][m] = rB[tp].x; Bs[buf][k4 + 1][m] = rB[tp].y;
            Bs[buf][k4 + 2][m] = rB[tp].z; Bs[buf][k4 + 3][m] = rB[tp].w;
        }
    };

    loadChunk(0);
    storeChunk(0);
    __syncthreads();
    int buf = 0;
    const int nch = K >> 4;
    for (int c = 0; c < nch; c++) {
        if (c + 1 < nch) loadChunk((c + 1) << 4);
#pragma unroll
        for (int k = 0; k < 16; k++) {
            float4 a0 = *(const float4*)&As[buf][k][ty * 4];
            float4 a1 = *(const float4*)&As[buf][k][64 + ty * 4];
            float4 b0 = *(const float4*)&Bs[buf][k][tx * 4];
            float4 b1 = *(const float4*)&Bs[buf][k][64 + tx * 4];
            float av0[4] = {a0.x, a0.y, a0.z, a0.w};
            float av1[4] = {a1.x, a1.y, a1.z, a1.w};
            float bv0[4] = {b0.x, b0.y, b0.z, b0.w};
            float bv1[4] = {b1.x, b1.y, b1.z, b1.w};
#pragma unroll
            for (int i = 0; i < 4; i++)
#pragma unroll
                for (int j = 0; j < 4; j++) {
                    acc[0][0][i][j] += av0[i] * bv0[j];
                    acc[0][1][i][j] += av0[i] * bv1[j];
                    acc[1][0][i][j] += av1[i] * bv0[j];
                    acc[1][1][i][j] += av1[i] * bv1[j];
                }
        }
        if (c + 1 < nch) storeChunk(buf ^ 1);
        __syncthreads();
        buf ^= 1;
    }

#pragma unroll
    for (int jj = 0; jj < 2; jj++) {
        int cglob = col0 + jj * 64 + tx * 4;
        float* Cb = C + (size_t)(cglob >> 10) * colSegStride + (cglob & 1023);
        float bb[4] = {bias[cglob + 0], bias[cglob + 1], bias[cglob + 2], bias[cglob + 3]};
#pragma unroll
        for (int ii = 0; ii < 2; ii++) {
#pragma unroll
            for (int i = 0; i < 4; i++) {
                int rr = row0 + ii * 64 + ty * 4 + i;
                int orow = out_base + (rr >> out_rshift) * out_stride + (rr & ((1 << out_rshift) - 1));
                float4 v;
                v.x = acc[ii][jj][i][0] + bb[0];
                v.y = acc[ii][jj][i][1] + bb[1];
                v.z = acc[ii][jj][i][2] + bb[2];
                v.w = acc[ii][jj][i][3] + bb[3];
                if (RELU) {
                    v.x = fmaxf(v.x, 0.f); v.y = fmaxf(v.y, 0.f);
                    v.z = fmaxf(v.z, 0.f); v.w = fmaxf(v.w, 0.f);
                }
                *(float4*)(Cb + (size_t)orow * 1024) = v;
            }
        }
    }
}

// ----------------------------------------------------------------------------
// flash-style fp32 attention: q-tile 64, k-tile 64, frag 4x4, Ks/Ps LDS union,
// register prefetch of next K/V tile, conflict-free LDS patterns. HD=64, S=2048.
__global__ __launch_bounds__(256, 3)
void attn_k(const float* __restrict__ Q, const float* __restrict__ Kb,
            const float* __restrict__ Vb, float* __restrict__ O)
{
    __shared__ float Qs[64][68];    // [d][q], Q pre-scaled by 1/8 (exact pow2)
    __shared__ float KPs[64][68];   // phase 1: K as [d][key]; phase 2: P as [q][key]
    __shared__ float Vs[64][72];    // [key][d]
    const int tid = threadIdx.x;
    const int tx = tid & 15, ty = tid >> 4;
    const int bh = blockIdx.x;            // 0..63
    const int b = bh >> 4, h = bh & 15;
    const int q0 = blockIdx.y * 64;
    const size_t qbase  = ((size_t)(b * 2048 + q0)) * 1024 + h * 64;
    const size_t kvbase = ((size_t)(b * 2048)) * 1024 + h * 64;

    const int m  = tid >> 2;          // 0..63 (16 distinct per wave -> conflict-free stores)
    const int c4 = (tid & 3) * 4;

    // stage Q transposed, scaled by 0.125 (exact: exponent shift only)
#pragma unroll
    for (int tp = 0; tp < 4; tp++) {
        int d4 = tp * 16 + c4;
        float4 v = *(const float4*)(Q + qbase + (size_t)m * 1024 + d4);
        Qs[d4 + 0][m] = v.x * 0.125f; Qs[d4 + 1][m] = v.y * 0.125f;
        Qs[d4 + 2][m] = v.z * 0.125f; Qs[d4 + 3][m] = v.w * 0.125f;
    }
    // prefetch K/V tile 0 into registers
    float4 kr[4], vr[4];
#pragma unroll
    for (int tp = 0; tp < 4; tp++) {
        int d4 = tp * 16 + c4;
        kr[tp] = *(const float4*)(Kb + kvbase + (size_t)m * 1024 + d4);
        vr[tp] = *(const float4*)(Vb + kvbase + (size_t)m * 1024 + d4);
    }
    float o[4][4] = {};
    float mrow[4], lrow[4];
#pragma unroll
    for (int i = 0; i < 4; i++) { mrow[i] = -INFINITY; lrow[i] = 0.f; }
    __syncthreads();   // Qs visible (and aligns phases)

    for (int kt = 0; kt < 32; kt++) {
        // store staged K/V (KPs region free: previous PV finished at loop-tail barrier)
#pragma unroll
        for (int tp = 0; tp < 4; tp++) {
            int d4 = tp * 16 + c4;
            KPs[d4 + 0][m] = kr[tp].x; KPs[d4 + 1][m] = kr[tp].y;
            KPs[d4 + 2][m] = kr[tp].z; KPs[d4 + 3][m] = kr[tp].w;
            *(float4*)&Vs[m][d4] = vr[tp];
        }
        __syncthreads();   // staging visible
        if (kt + 1 < 32) {  // prefetch next tile; in flight across QK compute
            size_t base2 = kvbase + (size_t)((kt + 1) * 64 + m) * 1024;
#pragma unroll
            for (int tp = 0; tp < 4; tp++) {
                int d4 = tp * 16 + c4;
                kr[tp] = *(const float4*)(Kb + base2 + d4);
                vr[tp] = *(const float4*)(Vb + base2 + d4);
            }
        }
        // QK^T
        float s[4][4] = {};
        for (int d = 0; d < 64; d++) {
            float4 qf = *(const float4*)&Qs[d][ty * 4];
            float4 kf = *(const float4*)&KPs[d][tx * 4];
            float qa[4] = {qf.x, qf.y, qf.z, qf.w};
            float ka[4] = {kf.x, kf.y, kf.z, kf.w};
#pragma unroll
            for (int i = 0; i < 4; i++)
#pragma unroll
                for (int j = 0; j < 4; j++)
                    s[i][j] += qa[i] * ka[j];
        }
        __syncthreads();   // all QK reads done -> KPs reusable for P
        // online softmax (rows = ty*4+i, reduce across tx lanes)
#pragma unroll
        for (int i = 0; i < 4; i++) {
            float rmax = fmaxf(fmaxf(s[i][0], s[i][1]), fmaxf(s[i][2], s[i][3]));
#pragma unroll
            for (int off = 1; off < 16; off <<= 1)
                rmax = fmaxf(rmax, __shfl_xor(rmax, off, 64));
            float mnew = fmaxf(mrow[i], rmax);
            float corr = expf(mrow[i] - mnew);
            float psum = 0.f;
#pragma unroll
            for (int j = 0; j < 4; j++) { float p = expf(s[i][j] - mnew); s[i][j] = p; psum += p; }
#pragma unroll
            for (int off = 1; off < 16; off <<= 1)
                psum += __shfl_xor(psum, off, 64);
            lrow[i] = lrow[i] * corr + psum;
#pragma unroll
            for (int j = 0; j < 4; j++) o[i][j] *= corr;
            mrow[i] = mnew;
            *(float4*)&KPs[ty * 4 + i][tx * 4] = make_float4(s[i][0], s[i][1], s[i][2], s[i][3]);
        }
        __syncthreads();   // P visible
        // P @ V  (quad-batched b128 reads)
#pragma unroll 4
        for (int kq = 0; kq < 16; kq++) {
            float4 pr0 = *(const float4*)&KPs[ty * 4 + 0][kq * 4];
            float4 pr1 = *(const float4*)&KPs[ty * 4 + 1][kq * 4];
            float4 pr2 = *(const float4*)&KPs[ty * 4 + 2][kq * 4];
            float4 pr3 = *(const float4*)&KPs[ty * 4 + 3][kq * 4];
            float4 v0 = *(const float4*)&Vs[kq * 4 + 0][tx * 4];
            float4 v1 = *(const float4*)&Vs[kq * 4 + 1][tx * 4];
            float4 v2 = *(const float4*)&Vs[kq * 4 + 2][tx * 4];
            float4 v3 = *(const float4*)&Vs[kq * 4 + 3][tx * 4];
            float pa[4][4] = {{pr0.x,pr0.y,pr0.z,pr0.w},{pr1.x,pr1.y,pr1.z,pr1.w},
                              {pr2.x,pr2.y,pr2.z,pr2.w},{pr3.x,pr3.y,pr3.z,pr3.w}};
            float va[4][4] = {{v0.x,v0.y,v0.z,v0.w},{v1.x,v1.y,v1.z,v1.w},
                              {v2.x,v2.y,v2.z,v2.w},{v3.x,v3.y,v3.z,v3.w}};
#pragma unroll
            for (int i = 0; i < 4; i++)
#pragma unroll
                for (int l = 0; l < 4; l++)
#pragma unroll
                    for (int j = 0; j < 4; j++)
                        o[i][j] += pa[i][l] * va[l][j];
        }
        __syncthreads();   // PV done -> KPs/Vs reusable next iteration
    }
#pragma unroll
    for (int i = 0; i < 4; i++) {
        float invl = 1.0f / lrow[i];
        int r = q0 + ty * 4 + i;
        float* orow = O + ((size_t)(b * 2048 + r)) * 1024 + h * 64 + tx * 4;
        float4 v;
        v.x = o[i][0] * invl; v.y = o[i][1] * invl;
        v.z = o[i][2] * invl; v.w = o[i][3] * invl;
        *(float4*)orow = v;
    }
}

// ----------------------------------------------------------------------------
// layernorm(X + T) * g + b, one block per row of 1024
__global__ __launch_bounds__(256)
void ln_k(const float* __restrict__ X, const float* __restrict__ T,
          const float* __restrict__ g, const float* __restrict__ bta,
          float* __restrict__ out)
{
    __shared__ float red[8];
    int r = blockIdx.x, tid = threadIdx.x;
    size_t base = (size_t)r * 1024 + tid * 4;
    float4 x  = *(const float4*)(X + base);
    float4 tk = *(const float4*)(T + base);
    x.x += tk.x; x.y += tk.y; x.z += tk.z; x.w += tk.w;
    float s = x.x + x.y + x.z + x.w;
#pragma unroll
    for (int off = 1; off < 64; off <<= 1) s += __shfl_xor(s, off, 64);
    int wv = tid >> 6;
    if ((tid & 63) == 0) red[wv] = s;
    __syncthreads();
    float mu = (red[0] + red[1] + red[2] + red[3]) * (1.0f / 1024.0f);
    float dx0 = x.x - mu, dx1 = x.y - mu, dx2 = x.z - mu, dx3 = x.w - mu;
    float ss = dx0 * dx0 + dx1 * dx1 + dx2 * dx2 + dx3 * dx3;
#pragma unroll
    for (int off = 1; off < 64; off <<= 1) ss += __shfl_xor(ss, off, 64);
    if ((tid & 63) == 0) red[4 + wv] = ss;
    __syncthreads();
    float var = (red[4] + red[5] + red[6] + red[7]) * (1.0f / 1024.0f);
    float inv = 1.0f / sqrtf(var + 1e-5f);
    float4 gg = *(const float4*)(g + tid * 4);
    float4 bb = *(const float4*)(bta + tid * 4);
    float4 y;
    y.x = dx0 * inv * gg.x + bb.x;
    y.y = dx1 * inv * gg.y + bb.y;
    y.z = dx2 * inv * gg.z + bb.z;
    y.w = dx3 * inv * gg.w + bb.w;
    *(float4*)(out + base) = y;
}

// ----------------------------------------------------------------------------
// logits[r][e] = dot(hidden[r], W2[e]) + b2[e] + eb[e]; one wave per row
__global__ __launch_bounds__(256)
void logits_k(const float* __restrict__ Hd, const float* __restrict__ W2,
              const float* __restrict__ b2, const float* __restrict__ eb,
              float* __restrict__ Lg)
{
    int gw = (blockIdx.x * 256 + threadIdx.x) >> 6;  // row 0..8191
    int lane = threadIdx.x & 63;
    const float* h = Hd + (size_t)gw * 1024;
    float4 hv[4];
#pragma unroll
    for (int j = 0; j < 4; j++) hv[j] = *(const float4*)(h + j * 256 + lane * 4);
    float res[8];
#pragma unroll
    for (int e = 0; e < 8; e++) {
        const float* w = W2 + (size_t)e * 1024;
        float acc = 0.f;
#pragma unroll
        for (int j = 0; j < 4; j++) {
            float4 w4 = *(const float4*)(w + j * 256 + lane * 4);
            acc += hv[j].x * w4.x + hv[j].y * w4.y + hv[j].z * w4.z + hv[j].w * w4.w;
        }
#pragma unroll
        for (int off = 1; off < 64; off <<= 1) acc += __shfl_xor(acc, off, 64);
        res[e] = acc;
    }
    if (lane < 8) {
        float v = res[0];
#pragma unroll
        for (int e = 1; e < 8; e++) v = (lane == e) ? res[e] : v;
        Lg[(size_t)gw * 8 + lane] = v + b2[lane] + eb[lane];
    }
}

// ----------------------------------------------------------------------------
// full routing epilogue: one thread per token
__global__ __launch_bounds__(256)
void router_k(const float* __restrict__ Lg, const int* __restrict__ t,
              float* __restrict__ outp, double* __restrict__ loadAcc)
{
    __shared__ double wred[4][8];
    int tid = threadIdx.x;
    int r = blockIdx.x * 256 + tid;   // 0..8191
    int b = r >> 11;
    float tn  = (float)t[b] / 1000.0f;
    float tau = 0.5f + 1.5f * tn;
    float p[8];
    float mx = -INFINITY;
#pragma unroll
    for (int e = 0; e < 8; e++) { p[e] = Lg[(size_t)r * 8 + e] / tau; mx = fmaxf(mx, p[e]); }
    float sum = 0.f;
#pragma unroll
    for (int e = 0; e < 8; e++) { p[e] = expf(p[e] - mx); sum += p[e]; }
#pragma unroll
    for (int e = 0; e < 8; e++) p[e] = p[e] / sum;
#pragma unroll
    for (int e = 0; e < 8; e++) p[e] = 0.85f * p[e] + 0.01875f;   // (1-ALPHA)p + ALPHA/E
    float w = 0.1f + 0.1f * tn;
    float shared_p = fmaxf(p[0], w);
    float osum = 0.f;
#pragma unroll
    for (int e = 1; e < 8; e++) osum += p[e];
    float denom_o = fmaxf(osum, 1e-8f);
    float one_m = 1.0f - shared_p;
    p[0] = shared_p;
#pragma unroll
    for (int e = 1; e < 8; e++) p[e] = (p[e] / denom_o) * one_m;  // match np op order
    int i0 = 0; float v0 = p[0];
#pragma unroll
    for (int e = 1; e < 8; e++) if (p[e] > v0) { v0 = p[e]; i0 = e; }
    int i1 = -1; float v1 = -INFINITY;
#pragma unroll
    for (int e = 0; e < 8; e++) if (e != i0 && p[e] > v1) { v1 = p[e]; i1 = e; }
    float cap = 0.5f + 0.1f * tn;
    float dsp[8], capped[8], hr[8];
    float exsum = 0.f, hsum = 0.f;
#pragma unroll
    for (int e = 0; e < 8; e++) {
        float d = ((e == i0) ? v0 : 0.f) + ((e == i1) ? v1 : 0.f);
        float ex = fmaxf(d - cap, 0.f);
        float c = d - ex;
        float h = fmaxf(cap - c, 0.f);
        capped[e] = c; hr[e] = h;
        exsum += ex; hsum += h;
    }
    float hden = fmaxf(hsum, 1e-8f);
    float dsum = 0.f;
#pragma unroll
    for (int e = 0; e < 8; e++) {
        float d = capped[e] + exsum * (hr[e] / hden);
        dsp[e] = d; dsum += d;
    }
    float cden = dsum + 1e-8f;
#pragma unroll
    for (int e = 0; e < 8; e++) {
        outp[(size_t)r * 8 + e] = dsp[e];
        outp[65536 + (size_t)r * 8 + e] = dsp[e] / cden;
    }
    int lane = tid & 63, wv = tid >> 6;
#pragma unroll
    for (int e = 0; e < 8; e++) {
        double s = (double)dsp[e];
#pragma unroll
        for (int off = 1; off < 64; off <<= 1) s += __shfl_xor(s, off, 64);
        if (lane == 0) wred[wv][e] = s;
    }
    __syncthreads();
    if (tid < 8) {
        double s = wred[0][tid] + wred[1][tid] + wred[2][tid] + wred[3][tid];
        atomicAdd(&loadAcc[tid], s);
    }
}

// ----------------------------------------------------------------------------
__global__ void penalty_k(const double* __restrict__ loadAcc, float* __restrict__ outp) {
    if (threadIdx.x == 0) {
        const float thr = (float)(2048.0 / 7.0 * 1.5);  // fair * 1.5
        float pen = 0.f;
#pragma unroll
        for (int e = 1; e < 8; e++) {
            float load = (float)(loadAcc[e] / 4.0);     // mean over B
            float x = fmaxf(load - thr, 0.f);
            pen += x * x;
        }
        outp[131072] = 0.01f * pen;
    }
}

// ----------------------------------------------------------------------------
extern "C" void kernel_launch(void* const* d_in, const int* in_sizes, int n_in,
                              void* d_out, int out_size, void* d_ws, size_t ws_size,
                              hipStream_t stream)
{
    const float* tokens = (const float*)d_in[0];
    const float* outA   = (const float*)d_in[1];
    const float* outC   = (const float*)d_in[2];
    const int*   tt     = (const int*)  d_in[3];
    const float* in_w   = (const float*)d_in[4];
    const float* in_b   = (const float*)d_in[5];
    const float* op_w   = (const float*)d_in[6];
    const float* op_b   = (const float*)d_in[7];
    const float* lng    = (const float*)d_in[8];
    const float* lnb    = (const float*)d_in[9];
    const float* te_w1  = (const float*)d_in[10];
    const float* te_b1  = (const float*)d_in[11];
    const float* te_w2  = (const float*)d_in[12];
    const float* te_b2  = (const float*)d_in[13];
    const float* g_w1   = (const float*)d_in[14];
    const float* g_b1   = (const float*)d_in[15];
    const float* g_w2   = (const float*)d_in[16];
    const float* g_b2   = (const float*)d_in[17];
    const float* e_bias = (const float*)d_in[18];
    float* out = (float*)d_out;

    float* ws = (float*)d_ws;
    const size_t NM = (size_t)8192 * 1024;
    float* bq   = ws;            // q proj -> later gate hidden
    float* bk   = ws + NM;       // k proj -> later ctx_B (post-LN)
    float* bv   = ws + 2 * NM;   // v proj -> later out_proj raw
    float* bo   = ws + 3 * NM;   // attention output
    float* temb   = ws + 4 * NM;        // 4x1024
    float* embb   = temb + 4096;        // 4x1024
    float* hte    = embb + 4096;        // 4x2048
    float* logitsb = hte + 8192;        // 8192x8
    double* loads = (double*)(logitsb + 65536);  // 8 doubles

    zero_k<<<1, 64, 0, stream>>>(loads);
    emb_k<<<4, 512, 0, stream>>>(tt, embb);
    te_fc_k<<<dim3(4, 128), 256, 0, stream>>>(embb, te_w1, te_b1, hte, 1024, 2048, 1);
    te_fc_k<<<dim3(4, 64),  256, 0, stream>>>(hte,  te_w2, te_b2, temb, 2048, 1024, 0);

    // q = tokens @ wq.T + bq
    gemm_k<false, false><<<dim3(64, 8), 256, 0, stream>>>(
        tokens, nullptr, nullptr, in_w, in_b, bq, 1024, 13, 0, 0, 0);
    // k & v together (cols 0..1023 -> bk, 1024..2047 -> bv=bk+NM), per-batch concat remap
    gemm_k<false, false><<<dim3(32, 16), 256, 0, stream>>>(
        outA, nullptr, nullptr, in_w + (size_t)1024 * 1024, in_b + 1024, bk, 1024, 10, 2048, 0, NM);
    gemm_k<false, false><<<dim3(32, 16), 256, 0, stream>>>(
        outC, nullptr, nullptr, in_w + (size_t)1024 * 1024, in_b + 1024, bk, 1024, 10, 2048, 1024, NM);

    attn_k<<<dim3(64, 32), 256, 0, stream>>>(bq, bk, bv, bo);

    // out_proj (into bv, free after attention)
    gemm_k<false, false><<<dim3(64, 8), 256, 0, stream>>>(
        bo, nullptr, nullptr, op_w, op_b, bv, 1024, 13, 0, 0, 0);
    // ctx_B = LN(out_proj + tokens) into bk
    ln_k<<<8192, 256, 0, stream>>>(bv, tokens, lng, lnb, bk);
    // gate hidden = relu([tokens | ctx_B | t_emb] @ gate_w1.T + b1) into bq
    gemm_k<true, true><<<dim3(64, 8), 256, 0, stream>>>(
        tokens, bk, temb, g_w1, g_b1, bq, 3072, 13, 0, 0, 0);

    logits_k<<<2048, 256, 0, stream>>>(bq, g_w2, g_b2, e_bias, logitsb);
    router_k<<<32, 256, 0, stream>>>(logitsb, tt, out, loads);
    penalty_k<<<1, 64, 0, stream>>>(loads, out);
}

// Round 3
// 2740.996 us; speedup vs baseline: 6.4454x; 6.4454x over previous
//
#include <hip/hip_runtime.h>
#include <math.h>

// Problem constants
//   B=4, NB=2048, NA=NC=1024, D=1024, E=8, H=16, HD=64, TOP_K=2
// All-fp32 implementation (no MFMA): top-2 routing makes numerics precision-critical.
// R3 note: NO lambdas capturing register arrays in hot kernels — R2's [&] lambdas
// caused scratch spills (VGPR 84, 32GB HBM fetch/dispatch, VALUBusy 6%).

// ----------------------------------------------------------------------------
__global__ void zero_k(double* p) {
    if (threadIdx.x < 8) p[threadIdx.x] = 0.0;
}

// ----------------------------------------------------------------------------
// sinusoidal time embedding: emb[b][0:512]=sin(t*freq), [512:1024]=cos(t*freq)
__global__ void emb_k(const int* __restrict__ t, float* __restrict__ emb) {
    int b = blockIdx.x;
    int j = threadIdx.x; // 0..511
    float x1 = (float)(-9.210340371976184) * (float)j;  // -log(10000) * j  (fp32, like np)
    float x2 = x1 / 511.0f;
    float freq = (float)exp((double)x2);
    float tf = (float)t[b];
    float arg = tf * freq;                               // fp32 product, like np
    emb[b * 1024 + j]       = (float)sin((double)arg);
    emb[b * 1024 + 512 + j] = (float)cos((double)arg);
}

// ----------------------------------------------------------------------------
// tiny FC for the time-embedding MLP
__global__ void te_fc_k(const float* __restrict__ in, const float* __restrict__ W,
                        const float* __restrict__ bias, float* __restrict__ out,
                        int K, int N, int do_silu) {
    int b = blockIdx.x;
    int wv = threadIdx.x >> 6, lane = threadIdx.x & 63;
    const float* inb = in + (size_t)b * K;
    int n0 = blockIdx.y * 16 + wv * 4;
    for (int q = 0; q < 4; q++) {
        int n = n0 + q;
        const float* wr = W + (size_t)n * K;
        float acc = 0.f;
        for (int c = lane * 4; c < K; c += 256) {
            float4 a  = *(const float4*)(inb + c);
            float4 w4 = *(const float4*)(wr + c);
            acc += a.x * w4.x + a.y * w4.y + a.z * w4.z + a.w * w4.w;
        }
#pragma unroll
        for (int off = 1; off < 64; off <<= 1) acc += __shfl_xor(acc, off, 64);
        if (lane == 0) {
            float x = acc + bias[n];
            out[(size_t)b * N + n] = do_silu ? (x / (1.0f + expf(-x))) : x;
        }
    }
}

// ----------------------------------------------------------------------------
// fp32 GEMM: C[orow(r), col] = dot(A[r,:K], W[col,:K]) + bias[col]  (W row-major (N,K))
// 128x128 tile, BK=16, 256 threads, split 4+4 fragments, single LDS buffer +
// register prefetch of the next chunk (explicit float4 locals, macro-expanded).
// GATE mode: K=3072 split across 3 A sources (tokens | ctxB | t_emb-per-batch).
// orow = base + (r>>rs)*stride + (r & ((1<<rs)-1))  (identity: rs=13, stride=0)
// colSegStride: output column c goes to C + (c>>10)*colSegStride + (c&1023)  (KV merge)

#define GEMM_LOAD_CHUNK(kk_) do {                                              \
    int kk = (kk_);                                                            \
    const float* Asel = A0; int colbase = kk;                                  \
    int ar0 = row0 + m0, ar1 = row0 + m1;                                      \
    if (GATE) {                                                                \
        int seg = kk >> 10;                                                    \
        if (seg == 1) Asel = A1; else if (seg == 2) Asel = A2;                 \
        colbase = kk & 1023;                                                   \
        if (seg == 2) { ar0 = (row0 + m0) >> 11; ar1 = (row0 + m1) >> 11; }    \
    }                                                                          \
    rA0 = *(const float4*)(Asel + (size_t)ar0 * 1024 + colbase + k4);          \
    rA1 = *(const float4*)(Asel + (size_t)ar1 * 1024 + colbase + k4);          \
    rB0 = *(const float4*)(W + (size_t)(col0 + m0) * K + kk + k4);             \
    rB1 = *(const float4*)(W + (size_t)(col0 + m1) * K + kk + k4);             \
} while (0)

#define GEMM_STORE_CHUNK() do {                                                \
    As[k4 + 0][m0] = rA0.x; As[k4 + 1][m0] = rA0.y;                            \
    As[k4 + 2][m0] = rA0.z; As[k4 + 3][m0] = rA0.w;                            \
    As[k4 + 0][m1] = rA1.x; As[k4 + 1][m1] = rA1.y;                            \
    As[k4 + 2][m1] = rA1.z; As[k4 + 3][m1] = rA1.w;                            \
    Bs[k4 + 0][m0] = rB0.x; Bs[k4 + 1][m0] = rB0.y;                            \
    Bs[k4 + 2][m0] = rB0.z; Bs[k4 + 3][m0] = rB0.w;                            \
    Bs[k4 + 0][m1] = rB1.x; Bs[k4 + 1][m1] = rB1.y;                            \
    Bs[k4 + 2][m1] = rB1.z; Bs[k4 + 3][m1] = rB1.w;                            \
} while (0)

template<bool GATE, bool RELU>
__global__ __launch_bounds__(256, 2)
void gemm_k(const float* __restrict__ A0, const float* __restrict__ A1,
            const float* __restrict__ A2,
            const float* __restrict__ W, const float* __restrict__ bias,
            float* __restrict__ C, int K,
            int out_rshift, int out_stride, int out_base, size_t colSegStride)
{
    __shared__ float As[16][132];
    __shared__ float Bs[16][132];
    const int tid = threadIdx.x;
    const int tx = tid & 15, ty = tid >> 4;
    const int row0 = blockIdx.x * 128;
    const int col0 = blockIdx.y * 128;
    const int m0 = tid >> 2;          // 0..63
    const int m1 = m0 + 64;           // 64..127
    const int k4 = (tid & 3) * 4;

    float acc[8][8];
#pragma unroll
    for (int i = 0; i < 8; i++)
#pragma unroll
        for (int j = 0; j < 8; j++) acc[i][j] = 0.f;

    float4 rA0, rA1, rB0, rB1;
    GEMM_LOAD_CHUNK(0);

    const int nch = K >> 4;
    for (int c = 0; c < nch; c++) {
        GEMM_STORE_CHUNK();
        __syncthreads();
        if (c + 1 < nch) GEMM_LOAD_CHUNK((c + 1) << 4);   // in flight during compute
#pragma unroll
        for (int k = 0; k < 16; k++) {
            float4 a0 = *(const float4*)&As[k][ty * 4];
            float4 a1 = *(const float4*)&As[k][64 + ty * 4];
            float4 b0 = *(const float4*)&Bs[k][tx * 4];
            float4 b1 = *(const float4*)&Bs[k][64 + tx * 4];
            float av[8] = {a0.x, a0.y, a0.z, a0.w, a1.x, a1.y, a1.z, a1.w};
            float bv[8] = {b0.x, b0.y, b0.z, b0.w, b1.x, b1.y, b1.z, b1.w};
#pragma unroll
            for (int i = 0; i < 8; i++)
#pragma unroll
                for (int j = 0; j < 8; j++)
                    acc[i][j] += av[i] * bv[j];
        }
        __syncthreads();
    }

#pragma unroll
    for (int i = 0; i < 8; i++) {
        int rr = row0 + ((i < 4) ? (ty * 4 + i) : (64 + ty * 4 + i - 4));
        int orow = out_base + (rr >> out_rshift) * out_stride + (rr & ((1 << out_rshift) - 1));
#pragma unroll
        for (int jj = 0; jj < 2; jj++) {
            int cglob = col0 + jj * 64 + tx * 4;
            float* Cb = C + (size_t)(cglob >> 10) * colSegStride + (cglob & 1023);
            float4 v;
            v.x = acc[i][jj * 4 + 0] + bias[cglob + 0];
            v.y = acc[i][jj * 4 + 1] + bias[cglob + 1];
            v.z = acc[i][jj * 4 + 2] + bias[cglob + 2];
            v.w = acc[i][jj * 4 + 3] + bias[cglob + 3];
            if (RELU) {
                v.x = fmaxf(v.x, 0.f); v.y = fmaxf(v.y, 0.f);
                v.z = fmaxf(v.z, 0.f); v.w = fmaxf(v.w, 0.f);
            }
            *(float4*)(Cb + (size_t)orow * 1024) = v;
        }
    }
}

// ----------------------------------------------------------------------------
// flash-style fp32 attention: q-tile 64, k-tile 64, frag 4x4, Ks/Ps LDS union,
// register prefetch of next K/V tile, conflict-free LDS patterns. HD=64, S=2048.
__global__ __launch_bounds__(256, 3)
void attn_k(const float* __restrict__ Q, const float* __restrict__ Kb,
            const float* __restrict__ Vb, float* __restrict__ O)
{
    __shared__ float Qs[64][68];    // [d][q], Q pre-scaled by 1/8 (exact pow2)
    __shared__ float KPs[64][68];   // phase 1: K as [d][key]; phase 2: P as [q][key]
    __shared__ float Vs[64][72];    // [key][d]
    const int tid = threadIdx.x;
    const int tx = tid & 15, ty = tid >> 4;
    const int bh = blockIdx.x;            // 0..63
    const int b = bh >> 4, h = bh & 15;
    const int q0 = blockIdx.y * 64;
    const size_t qbase  = ((size_t)(b * 2048 + q0)) * 1024 + h * 64;
    const size_t kvbase = ((size_t)(b * 2048)) * 1024 + h * 64;

    const int m  = tid >> 2;          // 0..63
    const int c4 = (tid & 3) * 4;

#pragma unroll
    for (int tp = 0; tp < 4; tp++) {
        int d4 = tp * 16 + c4;
        float4 v = *(const float4*)(Q + qbase + (size_t)m * 1024 + d4);
        Qs[d4 + 0][m] = v.x * 0.125f; Qs[d4 + 1][m] = v.y * 0.125f;
        Qs[d4 + 2][m] = v.z * 0.125f; Qs[d4 + 3][m] = v.w * 0.125f;
    }
    float4 kr[4], vr[4];
#pragma unroll
    for (int tp = 0; tp < 4; tp++) {
        int d4 = tp * 16 + c4;
        kr[tp] = *(const float4*)(Kb + kvbase + (size_t)m * 1024 + d4);
        vr[tp] = *(const float4*)(Vb + kvbase + (size_t)m * 1024 + d4);
    }
    float o[4][4] = {};
    float mrow[4], lrow[4];
#pragma unroll
    for (int i = 0; i < 4; i++) { mrow[i] = -INFINITY; lrow[i] = 0.f; }
    __syncthreads();

    for (int kt = 0; kt < 32; kt++) {
#pragma unroll
        for (int tp = 0; tp < 4; tp++) {
            int d4 = tp * 16 + c4;
            KPs[d4 + 0][m] = kr[tp].x; KPs[d4 + 1][m] = kr[tp].y;
            KPs[d4 + 2][m] = kr[tp].z; KPs[d4 + 3][m] = kr[tp].w;
            *(float4*)&Vs[m][d4] = vr[tp];
        }
        __syncthreads();
        if (kt + 1 < 32) {
            size_t base2 = kvbase + (size_t)((kt + 1) * 64 + m) * 1024;
#pragma unroll
            for (int tp = 0; tp < 4; tp++) {
                int d4 = tp * 16 + c4;
                kr[tp] = *(const float4*)(Kb + base2 + d4);
                vr[tp] = *(const float4*)(Vb + base2 + d4);
            }
        }
        float s[4][4] = {};
        for (int d = 0; d < 64; d++) {
            float4 qf = *(const float4*)&Qs[d][ty * 4];
            float4 kf = *(const float4*)&KPs[d][tx * 4];
            float qa[4] = {qf.x, qf.y, qf.z, qf.w};
            float ka[4] = {kf.x, kf.y, kf.z, kf.w};
#pragma unroll
            for (int i = 0; i < 4; i++)
#pragma unroll
                for (int j = 0; j < 4; j++)
                    s[i][j] += qa[i] * ka[j];
        }
        __syncthreads();
#pragma unroll
        for (int i = 0; i < 4; i++) {
            float rmax = fmaxf(fmaxf(s[i][0], s[i][1]), fmaxf(s[i][2], s[i][3]));
#pragma unroll
            for (int off = 1; off < 16; off <<= 1)
                rmax = fmaxf(rmax, __shfl_xor(rmax, off, 64));
            float mnew = fmaxf(mrow[i], rmax);
            float corr = expf(mrow[i] - mnew);
            float psum = 0.f;
#pragma unroll
            for (int j = 0; j < 4; j++) { float p = expf(s[i][j] - mnew); s[i][j] = p; psum += p; }
#pragma unroll
            for (int off = 1; off < 16; off <<= 1)
                psum += __shfl_xor(psum, off, 64);
            lrow[i] = lrow[i] * corr + psum;
#pragma unroll
            for (int j = 0; j < 4; j++) o[i][j] *= corr;
            mrow[i] = mnew;
            *(float4*)&KPs[ty * 4 + i][tx * 4] = make_float4(s[i][0], s[i][1], s[i][2], s[i][3]);
        }
        __syncthreads();
#pragma unroll 4
        for (int kq = 0; kq < 16; kq++) {
            float4 pr0 = *(const float4*)&KPs[ty * 4 + 0][kq * 4];
            float4 pr1 = *(const float4*)&KPs[ty * 4 + 1][kq * 4];
            float4 pr2 = *(const float4*)&KPs[ty * 4 + 2][kq * 4];
            float4 pr3 = *(const float4*)&KPs[ty * 4 + 3][kq * 4];
            float4 v0 = *(const float4*)&Vs[kq * 4 + 0][tx * 4];
            float4 v1 = *(const float4*)&Vs[kq * 4 + 1][tx * 4];
            float4 v2 = *(const float4*)&Vs[kq * 4 + 2][tx * 4];
            float4 v3 = *(const float4*)&Vs[kq * 4 + 3][tx * 4];
            float pa[4][4] = {{pr0.x,pr0.y,pr0.z,pr0.w},{pr1.x,pr1.y,pr1.z,pr1.w},
                              {pr2.x,pr2.y,pr2.z,pr2.w},{pr3.x,pr3.y,pr3.z,pr3.w}};
            float va[4][4] = {{v0.x,v0.y,v0.z,v0.w},{v1.x,v1.y,v1.z,v1.w},
                              {v2.x,v2.y,v2.z,v2.w},{v3.x,v3.y,v3.z,v3.w}};
#pragma unroll
            for (int i = 0; i < 4; i++)
#pragma unroll
                for (int l = 0; l < 4; l++)
#pragma unroll
                    for (int j = 0; j < 4; j++)
                        o[i][j] += pa[i][l] * va[l][j];
        }
        __syncthreads();
    }
#pragma unroll
    for (int i = 0; i < 4; i++) {
        float invl = 1.0f / lrow[i];
        int r = q0 + ty * 4 + i;
        float* orow = O + ((size_t)(b * 2048 + r)) * 1024 + h * 64 + tx * 4;
        float4 v;
        v.x = o[i][0] * invl; v.y = o[i][1] * invl;
        v.z = o[i][2] * invl; v.w = o[i][3] * invl;
        *(float4*)orow = v;
    }
}

// ----------------------------------------------------------------------------
// layernorm(X + T) * g + b, one block per row of 1024
__global__ __launch_bounds__(256)
void ln_k(const float* __restrict__ X, const float* __restrict__ T,
          const float* __restrict__ g, const float* __restrict__ bta,
          float* __restrict__ out)
{
    __shared__ float red[8];
    int r = blockIdx.x, tid = threadIdx.x;
    size_t base = (size_t)r * 1024 + tid * 4;
    float4 x  = *(const float4*)(X + base);
    float4 tk = *(const float4*)(T + base);
    x.x += tk.x; x.y += tk.y; x.z += tk.z; x.w += tk.w;
    float s = x.x + x.y + x.z + x.w;
#pragma unroll
    for (int off = 1; off < 64; off <<= 1) s += __shfl_xor(s, off, 64);
    int wv = tid >> 6;
    if ((tid & 63) == 0) red[wv] = s;
    __syncthreads();
    float mu = (red[0] + red[1] + red[2] + red[3]) * (1.0f / 1024.0f);
    float dx0 = x.x - mu, dx1 = x.y - mu, dx2 = x.z - mu, dx3 = x.w - mu;
    float ss = dx0 * dx0 + dx1 * dx1 + dx2 * dx2 + dx3 * dx3;
#pragma unroll
    for (int off = 1; off < 64; off <<= 1) ss += __shfl_xor(ss, off, 64);
    if ((tid & 63) == 0) red[4 + wv] = ss;
    __syncthreads();
    float var = (red[4] + red[5] + red[6] + red[7]) * (1.0f / 1024.0f);
    float inv = 1.0f / sqrtf(var + 1e-5f);
    float4 gg = *(const float4*)(g + tid * 4);
    float4 bb = *(const float4*)(bta + tid * 4);
    float4 y;
    y.x = dx0 * inv * gg.x + bb.x;
    y.y = dx1 * inv * gg.y + bb.y;
    y.z = dx2 * inv * gg.z + bb.z;
    y.w = dx3 * inv * gg.w + bb.w;
    *(float4*)(out + base) = y;
}

// ----------------------------------------------------------------------------
// logits[r][e] = dot(hidden[r], W2[e]) + b2[e] + eb[e]; one wave per row
__global__ __launch_bounds__(256)
void logits_k(const float* __restrict__ Hd, const float* __restrict__ W2,
              const float* __restrict__ b2, const float* __restrict__ eb,
              float* __restrict__ Lg)
{
    int gw = (blockIdx.x * 256 + threadIdx.x) >> 6;  // row 0..8191
    int lane = threadIdx.x & 63;
    const float* h = Hd + (size_t)gw * 1024;
    float4 hv[4];
#pragma unroll
    for (int j = 0; j < 4; j++) hv[j] = *(const float4*)(h + j * 256 + lane * 4);
    float res[8];
#pragma unroll
    for (int e = 0; e < 8; e++) {
        const float* w = W2 + (size_t)e * 1024;
        float acc = 0.f;
#pragma unroll
        for (int j = 0; j < 4; j++) {
            float4 w4 = *(const float4*)(w + j * 256 + lane * 4);
            acc += hv[j].x * w4.x + hv[j].y * w4.y + hv[j].z * w4.z + hv[j].w * w4.w;
        }
#pragma unroll
        for (int off = 1; off < 64; off <<= 1) acc += __shfl_xor(acc, off, 64);
        res[e] = acc;
    }
    if (lane < 8) {
        float v = res[0];
#pragma unroll
        for (int e = 1; e < 8; e++) v = (lane == e) ? res[e] : v;
        Lg[(size_t)gw * 8 + lane] = v + b2[lane] + eb[lane];
    }
}

// ----------------------------------------------------------------------------
// full routing epilogue: one thread per token
__global__ __launch_bounds__(256)
void router_k(const float* __restrict__ Lg, const int* __restrict__ t,
              float* __restrict__ outp, double* __restrict__ loadAcc)
{
    __shared__ double wred[4][8];
    int tid = threadIdx.x;
    int r = blockIdx.x * 256 + tid;   // 0..8191
    int b = r >> 11;
    float tn  = (float)t[b] / 1000.0f;
    float tau = 0.5f + 1.5f * tn;
    float p[8];
    float mx = -INFINITY;
#pragma unroll
    for (int e = 0; e < 8; e++) { p[e] = Lg[(size_t)r * 8 + e] / tau; mx = fmaxf(mx, p[e]); }
    float sum = 0.f;
#pragma unroll
    for (int e = 0; e < 8; e++) { p[e] = expf(p[e] - mx); sum += p[e]; }
#pragma unroll
    for (int e = 0; e < 8; e++) p[e] = p[e] / sum;
#pragma unroll
    for (int e = 0; e < 8; e++) p[e] = 0.85f * p[e] + 0.01875f;   // (1-ALPHA)p + ALPHA/E
    float w = 0.1f + 0.1f * tn;
    float shared_p = fmaxf(p[0], w);
    float osum = 0.f;
#pragma unroll
    for (int e = 1; e < 8; e++) osum += p[e];
    float denom_o = fmaxf(osum, 1e-8f);
    float one_m = 1.0f - shared_p;
    p[0] = shared_p;
#pragma unroll
    for (int e = 1; e < 8; e++) p[e] = (p[e] / denom_o) * one_m;  // match np op order
    int i0 = 0; float v0 = p[0];
#pragma unroll
    for (int e = 1; e < 8; e++) if (p[e] > v0) { v0 = p[e]; i0 = e; }
    int i1 = -1; float v1 = -INFINITY;
#pragma unroll
    for (int e = 0; e < 8; e++) if (e != i0 && p[e] > v1) { v1 = p[e]; i1 = e; }
    float cap = 0.5f + 0.1f * tn;
    float dsp[8], capped[8], hr[8];
    float exsum = 0.f, hsum = 0.f;
#pragma unroll
    for (int e = 0; e < 8; e++) {
        float d = ((e == i0) ? v0 : 0.f) + ((e == i1) ? v1 : 0.f);
        float ex = fmaxf(d - cap, 0.f);
        float c = d - ex;
        float h = fmaxf(cap - c, 0.f);
        capped[e] = c; hr[e] = h;
        exsum += ex; hsum += h;
    }
    float hden = fmaxf(hsum, 1e-8f);
    float dsum = 0.f;
#pragma unroll
    for (int e = 0; e < 8; e++) {
        float d = capped[e] + exsum * (hr[e] / hden);
        dsp[e] = d; dsum += d;
    }
    float cden = dsum + 1e-8f;
#pragma unroll
    for (int e = 0; e < 8; e++) {
        outp[(size_t)r * 8 + e] = dsp[e];
        outp[65536 + (size_t)r * 8 + e] = dsp[e] / cden;
    }
    int lane = tid & 63, wv = tid >> 6;
#pragma unroll
    for (int e = 0; e < 8; e++) {
        double s = (double)dsp[e];
#pragma unroll
        for (int off = 1; off < 64; off <<= 1) s += __shfl_xor(s, off, 64);
        if (lane == 0) wred[wv][e] = s;
    }
    __syncthreads();
    if (tid < 8) {
        double s = wred[0][tid] + wred[1][tid] + wred[2][tid] + wred[3][tid];
        atomicAdd(&loadAcc[tid], s);
    }
}

// ----------------------------------------------------------------------------
__global__ void penalty_k(const double* __restrict__ loadAcc, float* __restrict__ outp) {
    if (threadIdx.x == 0) {
        const float thr = (float)(2048.0 / 7.0 * 1.5);  // fair * 1.5
        float pen = 0.f;
#pragma unroll
        for (int e = 1; e < 8; e++) {
            float load = (float)(loadAcc[e] / 4.0);     // mean over B
            float x = fmaxf(load - thr, 0.f);
            pen += x * x;
        }
        outp[131072] = 0.01f * pen;
    }
}

// ----------------------------------------------------------------------------
extern "C" void kernel_launch(void* const* d_in, const int* in_sizes, int n_in,
                              void* d_out, int out_size, void* d_ws, size_t ws_size,
                              hipStream_t stream)
{
    const float* tokens = (const float*)d_in[0];
    const float* outA   = (const float*)d_in[1];
    const float* outC   = (const float*)d_in[2];
    const int*   tt     = (const int*)  d_in[3];
    const float* in_w   = (const float*)d_in[4];
    const float* in_b   = (const float*)d_in[5];
    const float* op_w   = (const float*)d_in[6];
    const float* op_b   = (const float*)d_in[7];
    const float* lng    = (const float*)d_in[8];
    const float* lnb    = (const float*)d_in[9];
    const float* te_w1  = (const float*)d_in[10];
    const float* te_b1  = (const float*)d_in[11];
    const float* te_w2  = (const float*)d_in[12];
    const float* te_b2  = (const float*)d_in[13];
    const float* g_w1   = (const float*)d_in[14];
    const float* g_b1   = (const float*)d_in[15];
    const float* g_w2   = (const float*)d_in[16];
    const float* g_b2   = (const float*)d_in[17];
    const float* e_bias = (const float*)d_in[18];
    float* out = (float*)d_out;

    float* ws = (float*)d_ws;
    const size_t NM = (size_t)8192 * 1024;
    float* bq   = ws;            // q proj -> later gate hidden
    float* bk   = ws + NM;       // k proj -> later ctx_B (post-LN)
    float* bv   = ws + 2 * NM;   // v proj -> later out_proj raw
    float* bo   = ws + 3 * NM;   // attention output
    float* temb   = ws + 4 * NM;        // 4x1024
    float* embb   = temb + 4096;        // 4x1024
    float* hte    = embb + 4096;        // 4x2048
    float* logitsb = hte + 8192;        // 8192x8
    double* loads = (double*)(logitsb + 65536);  // 8 doubles

    zero_k<<<1, 64, 0, stream>>>(loads);
    emb_k<<<4, 512, 0, stream>>>(tt, embb);
    te_fc_k<<<dim3(4, 128), 256, 0, stream>>>(embb, te_w1, te_b1, hte, 1024, 2048, 1);
    te_fc_k<<<dim3(4, 64),  256, 0, stream>>>(hte,  te_w2, te_b2, temb, 2048, 1024, 0);

    // q = tokens @ wq.T + bq
    gemm_k<false, false><<<dim3(64, 8), 256, 0, stream>>>(
        tokens, nullptr, nullptr, in_w, in_b, bq, 1024, 13, 0, 0, 0);
    // k & v together (cols 0..1023 -> bk, 1024..2047 -> bv=bk+NM), per-batch concat remap
    gemm_k<false, false><<<dim3(32, 16), 256, 0, stream>>>(
        outA, nullptr, nullptr, in_w + (size_t)1024 * 1024, in_b + 1024, bk, 1024, 10, 2048, 0, NM);
    gemm_k<false, false><<<dim3(32, 16), 256, 0, stream>>>(
        outC, nullptr, nullptr, in_w + (size_t)1024 * 1024, in_b + 1024, bk, 1024, 10, 2048, 1024, NM);

    attn_k<<<dim3(64, 32), 256, 0, stream>>>(bq, bk, bv, bo);

    // out_proj (into bv, free after attention)
    gemm_k<false, false><<<dim3(64, 8), 256, 0, stream>>>(
        bo, nullptr, nullptr, op_w, op_b, bv, 1024, 13, 0, 0, 0);
    // ctx_B = LN(out_proj + tokens) into bk
    ln_k<<<8192, 256, 0, stream>>>(bv, tokens, lng, lnb, bk);
    // gate hidden = relu([tokens | ctx_B | t_emb] @ gate_w1.T + b1) into bq
    gemm_k<true, true><<<dim3(64, 8), 256, 0, stream>>>(
        tokens, bk, temb, g_w1, g_b1, bq, 3072, 13, 0, 0, 0);

    logits_k<<<2048, 256, 0, stream>>>(bq, g_w2, g_b2, e_bias, logitsb);
    router_k<<<32, 256, 0, stream>>>(logitsb, tt, out, loads);
    penalty_k<<<1, 64, 0, stream>>>(loads, out);
}